// Round 8
// baseline (124.480 us; speedup 1.0000x reference)
//
#include <hip/hip_runtime.h>
#include <float.h>

#define DIM 64
#define NCODES 512
#define ROWS_PW 32   // rows per 1-wave block

typedef _Float16 half8 __attribute__((ext_vector_type(8)));
typedef float floatx4 __attribute__((ext_vector_type(4)));

// ws layout (float offsets):
//   et    fp32 [512][64]             @ 0
//   norms fp32 [512]                 @ 32768
//   ETh   f16 [8 chunk][512 k][8]    @ 33280
//   ETl   f16 [8 chunk][512 k][8]    @ 49664
#define WS_NORMS 32768
#define WS_ETH   33280
#define WS_ETL   49664

// Prep: transpose emb (D,K) -> fp32 et (K,D); norms; f16 hi/lo tables in
// [chunk][code] layout. Scaled lo split: el' = f16((e - f16(e)) * 2048).
__global__ __launch_bounds__(256) void vq_prep(const float* __restrict__ emb,
                                               float* __restrict__ ws,
                                               float* __restrict__ loss_slot) {
  __shared__ float T[64][65];
  const int tid = threadIdx.x;
  const int k0 = blockIdx.x * 64;
  if (blockIdx.x == 0 && tid == 0) loss_slot[0] = 0.0f;
#pragma unroll
  for (int j = 0; j < 16; ++j) {
    const int d = (tid >> 6) + j * 4;
    const int kl = tid & 63;
    T[d][kl] = emb[d * NCODES + k0 + kl];
  }
  __syncthreads();
  float* et = ws;
  float* norms = ws + WS_NORMS;
#pragma unroll
  for (int j = 0; j < 4; ++j) {
    const int f = tid + j * 256;
    const int kl = f >> 4;
    const int d4 = (f & 15) << 2;
    float4 q;
    q.x = T[d4 + 0][kl]; q.y = T[d4 + 1][kl];
    q.z = T[d4 + 2][kl]; q.w = T[d4 + 3][kl];
    *(float4*)&et[(size_t)(k0 + kl) * DIM + d4] = q;
  }
  if (tid < 64) {
    float s = 0.0f;
#pragma unroll
    for (int d = 0; d < DIM; ++d) s = fmaf(T[d][tid], T[d][tid], s);
    norms[k0 + tid] = s;
  }
  _Float16* eth = (_Float16*)(ws + WS_ETH);
  _Float16* etl = (_Float16*)(ws + WS_ETL);
#pragma unroll
  for (int i = 0; i < 4; ++i) {
    const int g = i * 256 + tid;
    const int split = g >> 9;
    const int h = (g >> 6) & 7;
    const int kl = g & 63;
    const int k = k0 + kl;
    half8 hv;
#pragma unroll
    for (int di = 0; di < 8; ++di) {
      const float v = T[h * 8 + di][kl];
      const _Float16 eh = (_Float16)v;
      const _Float16 el = (_Float16)((v - (float)eh) * 2048.0f);
      hv[di] = split ? el : eh;
    }
    *(half8*)((split ? etl : eth) + ((size_t)h * 512 + k) * 8) = hv;
  }
}

// Main: ONE wave per block (64 thr), 32 rows, all 512 codes. No LDS staging,
// no cross-wave barriers: ET f16 tables (128 KB total) stay L2-hot and are
// read as prefetched coalesced B-frags. Grid 2048 -> 8 independent waves/CU;
// phases of different waves overlap freely (round-7 lesson: the 1-block/CU
// 3-barrier structure serialized everything).
__global__ __launch_bounds__(64) void vq_main(const float* __restrict__ x,
                                              const float* __restrict__ ws,
                                              float* __restrict__ out,
                                              float* __restrict__ loss,
                                              float lscale) {
  __shared__ int sfk[ROWS_PW];

  const float* __restrict__ et = ws;
  const float* __restrict__ norms = ws + WS_NORMS;
  const _Float16* __restrict__ gh = (const _Float16*)(ws + WS_ETH);
  const _Float16* __restrict__ gl = (const _Float16*)(ws + WS_ETL);

  const int lane = threadIdx.x;
  const int col = lane & 15;
  const int quad = lane >> 4;
  const int row0 = blockIdx.x * ROWS_PW;

  // A-frags (guide layout A[m=lane&15][k=quad*8+j], verified in round 7):
  // 2 row-tiles x 2 ksteps, f16 hi + scaled lo; exact fp32 ||x||^2 alongside.
  half8 ah[2][2], al[2][2];
  float xn[2] = {0.0f, 0.0f};
#pragma unroll
  for (int rt = 0; rt < 2; ++rt) {
#pragma unroll
    for (int ks = 0; ks < 2; ++ks) {
      const float4* xp = (const float4*)x +
                         (size_t)(row0 + rt * 16 + col) * 16 + ks * 8 + quad * 2;
      const float4 f0 = xp[0], f1 = xp[1];
      const float f[8] = {f0.x, f0.y, f0.z, f0.w, f1.x, f1.y, f1.z, f1.w};
#pragma unroll
      for (int j = 0; j < 8; ++j) {
        const float v = f[j];
        xn[rt] = fmaf(v, v, xn[rt]);
        const _Float16 h = (_Float16)v;
        ah[rt][ks][j] = h;
        al[rt][ks][j] = (_Float16)((v - (float)h) * 2048.0f);
      }
    }
    xn[rt] += __shfl_xor(xn[rt], 16);  // sum quads -> full row norm
    xn[rt] += __shfl_xor(xn[rt], 32);
  }

  // Per-lane B-frag base pointers: chunk (ks*4+quad), code (n0+col).
  const _Float16* ph0 = gh + ((size_t)(0 + quad) * 512 + col) * 8;
  const _Float16* ph1 = gh + ((size_t)(4 + quad) * 512 + col) * 8;
  const _Float16* pl0 = gl + ((size_t)(0 + quad) * 512 + col) * 8;
  const _Float16* pl1 = gl + ((size_t)(4 + quad) * 512 + col) * 8;

  float best[2][4];
  int bk[2][4];
#pragma unroll
  for (int rt = 0; rt < 2; ++rt)
#pragma unroll
    for (int r = 0; r < 4; ++r) { best[rt][r] = FLT_MAX; bk[rt][r] = 0; }

  // Prefetch ct=0
  half8 cbh0 = *(const half8*)ph0, cbh1 = *(const half8*)ph1;
  half8 cbl0 = *(const half8*)pl0, cbl1 = *(const half8*)pl1;
  float cnk = norms[col];

#pragma unroll 1
  for (int ct = 0; ct < 32; ++ct) {
    half8 nbh0, nbh1, nbl0, nbl1;
    float nnk = 0.0f;
    if (ct < 31) {  // issue next tile's loads before this tile's MFMAs
      const int o = (ct + 1) * 16 * 8;  // halves: 16 codes x 8
      nbh0 = *(const half8*)(ph0 + o); nbh1 = *(const half8*)(ph1 + o);
      nbl0 = *(const half8*)(pl0 + o); nbl1 = *(const half8*)(pl1 + o);
      nnk = norms[(ct + 1) * 16 + col];
    }
    const int k = ct * 16 + col;  // this lane's code (ascending in ct)
#pragma unroll
    for (int rt = 0; rt < 2; ++rt) {
      floatx4 hh = {0.f, 0.f, 0.f, 0.f};
      floatx4 cr0 = {0.f, 0.f, 0.f, 0.f}, cr1 = {0.f, 0.f, 0.f, 0.f};
      hh = __builtin_amdgcn_mfma_f32_16x16x32_f16(ah[rt][0], cbh0, hh, 0, 0, 0);
      hh = __builtin_amdgcn_mfma_f32_16x16x32_f16(ah[rt][1], cbh1, hh, 0, 0, 0);
      cr0 = __builtin_amdgcn_mfma_f32_16x16x32_f16(al[rt][0], cbh0, cr0, 0, 0, 0);
      cr0 = __builtin_amdgcn_mfma_f32_16x16x32_f16(ah[rt][0], cbl0, cr0, 0, 0, 0);
      cr1 = __builtin_amdgcn_mfma_f32_16x16x32_f16(al[rt][1], cbh1, cr1, 0, 0, 0);
      cr1 = __builtin_amdgcn_mfma_f32_16x16x32_f16(ah[rt][1], cbl1, cr1, 0, 0, 0);
#pragma unroll
      for (int r = 0; r < 4; ++r) {
        const float s = fmaf(cr0[r] + cr1[r], 4.8828125e-4f, hh[r]);
        const float dist = fmaf(s, -2.0f, cnk);  // ||x||^2 dropped (argmin-inv)
        if (dist < best[rt][r]) { best[rt][r] = dist; bk[rt][r] = k; }
      }
    }
    cbh0 = nbh0; cbh1 = nbh1; cbl0 = nbl0; cbl1 = nbl1; cnk = nnk;
  }

  // Reduce over the 16 col-lanes (xor butterfly); tie -> smaller k (np.argmin)
#pragma unroll
  for (int off = 1; off < 16; off <<= 1) {
#pragma unroll
    for (int rt = 0; rt < 2; ++rt)
#pragma unroll
      for (int r = 0; r < 4; ++r) {
        const float ob = __shfl_xor(best[rt][r], off);
        const int ok = __shfl_xor(bk[rt][r], off);
        if (ob < best[rt][r] || (ob == best[rt][r] && ok < bk[rt][r])) {
          best[rt][r] = ob; bk[rt][r] = ok;
        }
      }
  }

  // Loss: ||x-q||^2 = best + ||x||^2
  float ls = 0.0f;
#pragma unroll
  for (int rt = 0; rt < 2; ++rt)
#pragma unroll
    for (int r = 0; r < 4; ++r) {
      const int m = quad * 4 + r;
      const float xnm = __shfl(xn[rt], (lane & 48) | m, 64);
      ls += best[rt][r] + xnm;
    }
  ls = (col == 0) ? ls : 0.0f;
  ls += __shfl_xor(ls, 16);
  ls += __shfl_xor(ls, 32);
  if (lane == 0) atomicAdd(loss, ls * lscale);

  if (col == 0) {
#pragma unroll
    for (int rt = 0; rt < 2; ++rt)
#pragma unroll
      for (int r = 0; r < 4; ++r)
        sfk[rt * 16 + quad * 4 + r] = bk[rt][r];
  }
  __syncthreads();  // single-wave block: cheap

  // Epilogue: gather winning fp32 code rows (et is L2-hot), coalesced stores
  {
    float* __restrict__ o = out + (size_t)row0 * DIM;
#pragma unroll
    for (int j = 0; j < 8; ++j) {
      const int f = lane + j * 64;   // 0..511
      const int r = f >> 4;          // row 0..31
      const int c = (f & 15) << 2;   // col 0..60
      const int k = sfk[r];
      *(float4*)&o[(size_t)r * DIM + c] = *(const float4*)&et[(size_t)k * DIM + c];
    }
  }
}

extern "C" void kernel_launch(void* const* d_in, const int* in_sizes, int n_in,
                              void* d_out, int out_size, void* d_ws, size_t ws_size,
                              hipStream_t stream) {
  const float* x = (const float*)d_in[0];    // (64,32,32,64) fp32
  const float* emb = (const float*)d_in[1];  // (64,512) fp32
  float* out = (float*)d_out;                // out (4194304) + loss (1)

  const int nrows = in_sizes[0] / DIM;       // 65536
  float* ws = (float*)d_ws;                  // 264 KB used
  float* loss = out + (out_size - 1);

  vq_prep<<<NCODES / 64, 256, 0, stream>>>(emb, ws, loss);

  const float lscale = 1.25f / (float)(nrows * DIM);  // (1+beta)/numel
  vq_main<<<nrows / ROWS_PW, 64, 0, stream>>>(x, ws, out, loss, lscale);
}

// Round 9
// 113.554 us; speedup vs baseline: 1.0962x; 1.0962x over previous
//
#include <hip/hip_runtime.h>
#include <float.h>

#define DIM 64
#define NCODES 512
#define ROWS_PW 64   // rows per 1-wave block (4 row-tiles of 16)

typedef _Float16 half8 __attribute__((ext_vector_type(8)));
typedef float floatx4 __attribute__((ext_vector_type(4)));

// ws layout (float offsets):
//   et    fp32 [512][64]             @ 0
//   norms fp32 [512]                 @ 32768
//   ETh   f16 [8 chunk][512 k][8]    @ 33280
//   ETl   f16 [8 chunk][512 k][8]    @ 49664
#define WS_NORMS 32768
#define WS_ETH   33280
#define WS_ETL   49664

// Prep: transpose emb (D,K) -> fp32 et (K,D); norms; f16 hi/lo tables in
// [chunk][code] layout. Scaled lo split: el' = f16((e - f16(e)) * 2048).
__global__ __launch_bounds__(256) void vq_prep(const float* __restrict__ emb,
                                               float* __restrict__ ws,
                                               float* __restrict__ loss_slot) {
  __shared__ float T[64][65];
  const int tid = threadIdx.x;
  const int k0 = blockIdx.x * 64;
  if (blockIdx.x == 0 && tid == 0) loss_slot[0] = 0.0f;
#pragma unroll
  for (int j = 0; j < 16; ++j) {
    const int d = (tid >> 6) + j * 4;
    const int kl = tid & 63;
    T[d][kl] = emb[d * NCODES + k0 + kl];
  }
  __syncthreads();
  float* et = ws;
  float* norms = ws + WS_NORMS;
#pragma unroll
  for (int j = 0; j < 4; ++j) {
    const int f = tid + j * 256;
    const int kl = f >> 4;
    const int d4 = (f & 15) << 2;
    float4 q;
    q.x = T[d4 + 0][kl]; q.y = T[d4 + 1][kl];
    q.z = T[d4 + 2][kl]; q.w = T[d4 + 3][kl];
    *(float4*)&et[(size_t)(k0 + kl) * DIM + d4] = q;
  }
  if (tid < 64) {
    float s = 0.0f;
#pragma unroll
    for (int d = 0; d < DIM; ++d) s = fmaf(T[d][tid], T[d][tid], s);
    norms[k0 + tid] = s;
  }
  _Float16* eth = (_Float16*)(ws + WS_ETH);
  _Float16* etl = (_Float16*)(ws + WS_ETL);
#pragma unroll
  for (int i = 0; i < 4; ++i) {
    const int g = i * 256 + tid;
    const int split = g >> 9;
    const int h = (g >> 6) & 7;
    const int kl = g & 63;
    const int k = k0 + kl;
    half8 hv;
#pragma unroll
    for (int di = 0; di < 8; ++di) {
      const float v = T[h * 8 + di][kl];
      const _Float16 eh = (_Float16)v;
      const _Float16 el = (_Float16)((v - (float)eh) * 2048.0f);
      hv[di] = split ? el : eh;
    }
    *(half8*)((split ? etl : eth) + ((size_t)h * 512 + k) * 8) = hv;
  }
}

// Main: ONE wave per block, 64 rows (4 row-tiles), all 512 codes, no barriers.
// Round-8 lesson: prefetch-1 (58 cyc) << L2 latency (~200 cyc) -> every tile
// stalled. Now: 24 MFMAs/tile (4 row-tiles) + prefetch distance 2 via manual
// 2x unroll with rotating register buffers -> ~450 cyc of issue between a
// B-frag load and its consumption, covering L2 latency within a single wave.
__global__ __launch_bounds__(64) void vq_main(const float* __restrict__ x,
                                              const float* __restrict__ ws,
                                              float* __restrict__ out,
                                              float* __restrict__ loss,
                                              float lscale) {
  __shared__ int sfk[ROWS_PW];

  const float* __restrict__ et = ws;
  const float* __restrict__ norms = ws + WS_NORMS;
  const _Float16* __restrict__ gh = (const _Float16*)(ws + WS_ETH);
  const _Float16* __restrict__ gl = (const _Float16*)(ws + WS_ETL);

  const int lane = threadIdx.x;
  const int col = lane & 15;
  const int quad = lane >> 4;
  const int row0 = blockIdx.x * ROWS_PW;

  // A-frags (A[m=lane&15][k=quad*8+j], round-7-verified): 4 row-tiles x
  // 2 ksteps, f16 hi + scaled lo; exact fp32 ||x||^2 alongside.
  half8 ah[4][2], al[4][2];
  float xn[4];
#pragma unroll
  for (int rt = 0; rt < 4; ++rt) {
    xn[rt] = 0.0f;
#pragma unroll
    for (int ks = 0; ks < 2; ++ks) {
      const float4* xp = (const float4*)x +
                         (size_t)(row0 + rt * 16 + col) * 16 + ks * 8 + quad * 2;
      const float4 f0 = xp[0], f1 = xp[1];
      const float f[8] = {f0.x, f0.y, f0.z, f0.w, f1.x, f1.y, f1.z, f1.w};
#pragma unroll
      for (int j = 0; j < 8; ++j) {
        const float v = f[j];
        xn[rt] = fmaf(v, v, xn[rt]);
        const _Float16 h = (_Float16)v;
        ah[rt][ks][j] = h;
        al[rt][ks][j] = (_Float16)((v - (float)h) * 2048.0f);
      }
    }
    xn[rt] += __shfl_xor(xn[rt], 16);  // sum quads -> full row norm
    xn[rt] += __shfl_xor(xn[rt], 32);
  }

  // Per-lane B-frag base pointers: chunk (ks*4+quad), code col.
  const _Float16* ph0 = gh + ((size_t)(0 + quad) * 512 + col) * 8;
  const _Float16* ph1 = gh + ((size_t)(4 + quad) * 512 + col) * 8;
  const _Float16* pl0 = gl + ((size_t)(0 + quad) * 512 + col) * 8;
  const _Float16* pl1 = gl + ((size_t)(4 + quad) * 512 + col) * 8;

  float best[4][4];
  int bk[4][4];
#pragma unroll
  for (int rt = 0; rt < 4; ++rt)
#pragma unroll
    for (int r = 0; r < 4; ++r) { best[rt][r] = FLT_MAX; bk[rt][r] = 0; }

  // Rotating buffers: b0 = even tile, b1 = odd tile. Preload tiles 0,1.
  half8 b0h0 = *(const half8*)(ph0), b0h1 = *(const half8*)(ph1);
  half8 b0l0 = *(const half8*)(pl0), b0l1 = *(const half8*)(pl1);
  float n0k = norms[col];
  half8 b1h0 = *(const half8*)(ph0 + 128), b1h1 = *(const half8*)(ph1 + 128);
  half8 b1l0 = *(const half8*)(pl0 + 128), b1l1 = *(const half8*)(pl1 + 128);
  float n1k = norms[16 + col];

#pragma unroll 1
  for (int ct = 0; ct < 32; ct += 2) {
    // ---- prefetch tile ct+2 (clamped: harmless re-read of tile 31) ----
    const int p0 = (ct + 2 < 32) ? (ct + 2) : 31;
    const int o0 = p0 * 128;
    const half8 t0h0 = *(const half8*)(ph0 + o0), t0h1 = *(const half8*)(ph1 + o0);
    const half8 t0l0 = *(const half8*)(pl0 + o0), t0l1 = *(const half8*)(pl1 + o0);
    const float tn0 = norms[p0 * 16 + col];
    // ---- compute tile ct from b0 ----
    {
      const int k = ct * 16 + col;
#pragma unroll
      for (int rt = 0; rt < 4; ++rt) {
        floatx4 hh = {0.f, 0.f, 0.f, 0.f};
        floatx4 cr0 = {0.f, 0.f, 0.f, 0.f}, cr1 = {0.f, 0.f, 0.f, 0.f};
        hh = __builtin_amdgcn_mfma_f32_16x16x32_f16(ah[rt][0], b0h0, hh, 0, 0, 0);
        hh = __builtin_amdgcn_mfma_f32_16x16x32_f16(ah[rt][1], b0h1, hh, 0, 0, 0);
        cr0 = __builtin_amdgcn_mfma_f32_16x16x32_f16(al[rt][0], b0h0, cr0, 0, 0, 0);
        cr0 = __builtin_amdgcn_mfma_f32_16x16x32_f16(ah[rt][0], b0l0, cr0, 0, 0, 0);
        cr1 = __builtin_amdgcn_mfma_f32_16x16x32_f16(al[rt][1], b0h1, cr1, 0, 0, 0);
        cr1 = __builtin_amdgcn_mfma_f32_16x16x32_f16(ah[rt][1], b0l1, cr1, 0, 0, 0);
#pragma unroll
        for (int r = 0; r < 4; ++r) {
          const float s = fmaf(cr0[r] + cr1[r], 4.8828125e-4f, hh[r]);
          const float dist = fmaf(s, -2.0f, n0k);  // ||x||^2 dropped
          if (dist < best[rt][r]) { best[rt][r] = dist; bk[rt][r] = k; }
        }
      }
    }
    // ---- prefetch tile ct+3 (clamped) ----
    const int p1 = (ct + 3 < 32) ? (ct + 3) : 31;
    const int o1 = p1 * 128;
    const half8 t1h0 = *(const half8*)(ph0 + o1), t1h1 = *(const half8*)(ph1 + o1);
    const half8 t1l0 = *(const half8*)(pl0 + o1), t1l1 = *(const half8*)(pl1 + o1);
    const float tn1 = norms[p1 * 16 + col];
    // ---- compute tile ct+1 from b1 ----
    {
      const int k = (ct + 1) * 16 + col;
#pragma unroll
      for (int rt = 0; rt < 4; ++rt) {
        floatx4 hh = {0.f, 0.f, 0.f, 0.f};
        floatx4 cr0 = {0.f, 0.f, 0.f, 0.f}, cr1 = {0.f, 0.f, 0.f, 0.f};
        hh = __builtin_amdgcn_mfma_f32_16x16x32_f16(ah[rt][0], b1h0, hh, 0, 0, 0);
        hh = __builtin_amdgcn_mfma_f32_16x16x32_f16(ah[rt][1], b1h1, hh, 0, 0, 0);
        cr0 = __builtin_amdgcn_mfma_f32_16x16x32_f16(al[rt][0], b1h0, cr0, 0, 0, 0);
        cr0 = __builtin_amdgcn_mfma_f32_16x16x32_f16(ah[rt][0], b1l0, cr0, 0, 0, 0);
        cr1 = __builtin_amdgcn_mfma_f32_16x16x32_f16(al[rt][1], b1h1, cr1, 0, 0, 0);
        cr1 = __builtin_amdgcn_mfma_f32_16x16x32_f16(ah[rt][1], b1l1, cr1, 0, 0, 0);
#pragma unroll
        for (int r = 0; r < 4; ++r) {
          const float s = fmaf(cr0[r] + cr1[r], 4.8828125e-4f, hh[r]);
          const float dist = fmaf(s, -2.0f, n1k);
          if (dist < best[rt][r]) { best[rt][r] = dist; bk[rt][r] = k; }
        }
      }
    }
    // rotate
    b0h0 = t0h0; b0h1 = t0h1; b0l0 = t0l0; b0l1 = t0l1; n0k = tn0;
    b1h0 = t1h0; b1h1 = t1h1; b1l0 = t1l0; b1l1 = t1l1; n1k = tn1;
  }

  // Reduce over the 16 col-lanes (xor butterfly); tie -> smaller k (np.argmin)
#pragma unroll
  for (int off = 1; off < 16; off <<= 1) {
#pragma unroll
    for (int rt = 0; rt < 4; ++rt)
#pragma unroll
      for (int r = 0; r < 4; ++r) {
        const float ob = __shfl_xor(best[rt][r], off);
        const int ok = __shfl_xor(bk[rt][r], off);
        if (ob < best[rt][r] || (ob == best[rt][r] && ok < bk[rt][r])) {
          best[rt][r] = ob; bk[rt][r] = ok;
        }
      }
  }

  // Loss: ||x-q||^2 = best + ||x||^2
  float ls = 0.0f;
#pragma unroll
  for (int rt = 0; rt < 4; ++rt)
#pragma unroll
    for (int r = 0; r < 4; ++r) {
      const int m = quad * 4 + r;
      const float xnm = __shfl(xn[rt], (lane & 48) | m, 64);
      ls += best[rt][r] + xnm;
    }
  ls = (col == 0) ? ls : 0.0f;
  ls += __shfl_xor(ls, 16);
  ls += __shfl_xor(ls, 32);
  if (lane == 0) atomicAdd(loss, ls * lscale);

  if (col == 0) {
#pragma unroll
    for (int rt = 0; rt < 4; ++rt)
#pragma unroll
      for (int r = 0; r < 4; ++r)
        sfk[rt * 16 + quad * 4 + r] = bk[rt][r];
  }
  __syncthreads();  // single-wave block: cheap

  // Epilogue: gather winning fp32 code rows (et is L2-hot), coalesced stores
  {
    float* __restrict__ o = out + (size_t)row0 * DIM;
#pragma unroll
    for (int j = 0; j < 16; ++j) {
      const int f = lane + j * 64;   // 0..1023
      const int r = f >> 4;          // row 0..63
      const int c = (f & 15) << 2;   // col 0..60
      const int k = sfk[r];
      *(float4*)&o[(size_t)r * DIM + c] = *(const float4*)&et[(size_t)k * DIM + c];
    }
  }
}

extern "C" void kernel_launch(void* const* d_in, const int* in_sizes, int n_in,
                              void* d_out, int out_size, void* d_ws, size_t ws_size,
                              hipStream_t stream) {
  const float* x = (const float*)d_in[0];    // (64,32,32,64) fp32
  const float* emb = (const float*)d_in[1];  // (64,512) fp32
  float* out = (float*)d_out;                // out (4194304) + loss (1)

  const int nrows = in_sizes[0] / DIM;       // 65536
  float* ws = (float*)d_ws;                  // 264 KB used
  float* loss = out + (out_size - 1);

  vq_prep<<<NCODES / 64, 256, 0, stream>>>(emb, ws, loss);

  const float lscale = 1.25f / (float)(nrows * DIM);  // (1+beta)/numel
  vq_main<<<nrows / ROWS_PW, 64, 0, stream>>>(x, ws, out, loss, lscale);
}